// Round 15
// baseline (52.459 us; speedup 1.0000x reference)
//
#include <hip/hip_runtime.h>

#define WIN    7
#define IMH    640
#define IMW    640
#define OHH    634            // IMH - WIN + 1
#define OWW    634
#define NB     64
#define NBANDS 32
#define BROWS  20             // 31*20 + 14 = 634 output rows
#define NCT    5              // column tiles of 128 output cols
#define NTASK  (NB * NBANDS * NCT)   // 10240 wave-tasks
#define WPB    4              // waves per block (256 threads)
#define NBLK   (NTASK / WPB)  // 2560 blocks
#define RDEPTH 4              // rows held in regs (load -> ds_write distance)
#define TCOLS  136            // staged cols per tile: 128 + 8 halo
#define SSTR   (2 * TCOLS)    // LDS slot stride in floats

typedef float v2f __attribute__((ext_vector_type(2)));

// Cooperative-staged band loop. Each lane loads only its own float2 per image
// per row (coalesced 512B/wave-row vs r13's 4x-overlapping 16B loads),
// computes (s,d) once per column, stages into a 2-slot wave-private LDS ring,
// and reads its 8-col window back as v2f pairs.
//
// ORDERING (r14 failure root cause): the window reads are CROSS-LANE (lane l
// consumes lanes l+1..l+3's writes). Per-lane alias analysis sees disjoint
// constant offsets and may reorder ds_read above the producing ds_write.
// Fix: __builtin_amdgcn_wave_barrier() (+ sched_barrier) at the top of the
// read region, with WRITER at the END of the body so ONE fence per iteration
// separates both W(u)->R(u) (RAW) and R(u)->W(u+2) (WAR, same slot). HW DS is
// in-order per wave, so no lgkmcnt wait is needed once compiler order holds.
template<int NROWS>
__device__ double band_loop(const float* __restrict__ Xb,
                            const float* __restrict__ Yb,
                            float* __restrict__ sS, float* __restrict__ sD,
                            int lane, int c0, int hc,
                            float C1s, float C2s, bool active)
{
    const v2f C1v  = {C1s, C1s};
    const v2f C2v  = {C2s, C2s};
    const v2f covh = {(49.0f / 48.0f) * 0.5f, (49.0f / 48.0f) * 0.5f};
    const v2f zero = {0.f, 0.f};

    v2f rS[WIN], rD[WIN], rSS[WIN], rDD[WIN];
    #pragma unroll
    for (int u = 0; u < WIN; ++u) { rS[u]=zero; rD[u]=zero; rSS[u]=zero; rDD[u]=zero; }
    v2f VS = zero, VD = zero, VSS = zero, VDD = zero;

    v2f gx[RDEPTH], gy[RDEPTH], hx[RDEPTH], hy[RDEPTH];
    double acc  = 0.0;
    float  esum = 0.f;

#define LOADR(K, R) do {                                                      \
    const float* xr_ = Xb + (size_t)(R) * IMW;                                \
    const float* yr_ = Yb + (size_t)(R) * IMW;                                \
    gx[K] = *(const v2f*)(xr_ + c0);  gy[K] = *(const v2f*)(yr_ + c0);        \
    hx[K] = *(const v2f*)(xr_ + hc);  hy[K] = *(const v2f*)(yr_ + hc);        \
} while (0)

#define WRITER(K, SL) do {                                                    \
    const v2f s_ = gx[K] + gy[K], d_ = gx[K] - gy[K];                         \
    *(v2f*)(sS + (SL) * SSTR + 2 * lane) = s_;                                \
    *(v2f*)(sD + (SL) * SSTR + 2 * lane) = d_;                                \
    if (lane < 4) {                                                           \
        const v2f hs_ = hx[K] + hy[K], hd_ = hx[K] - hy[K];                   \
        *(v2f*)(sS + (SL) * SSTR + 128 + 2 * lane) = hs_;                     \
        *(v2f*)(sD + (SL) * SSTR + 128 + 2 * lane) = hd_;                     \
    }                                                                         \
} while (0)

    // prologue: rows 0..3 in regs, row 0 staged to LDS slot 0
    LOADR(0, 0); LOADR(1, 1); LOADR(2, 2); LOADR(3, 3);
    WRITER(0, 0);

    #pragma unroll
    for (int u = 0; u < NROWS; ++u) {
        if (u + RDEPTH < NROWS) LOADR((u + RDEPTH) & 3, u + RDEPTH);  // static idx

        // fence: prior WRITER's ds_writes must stay above this iter's reads,
        // and prior iter's reads above the next WRITER (cross-lane deps are
        // invisible to per-lane alias analysis — r14 lesson).
        __builtin_amdgcn_wave_barrier();
        __builtin_amdgcn_sched_barrier(0);

        {
            // read (s,d) window pairs: cols 2l..2l+7 of staged row u
            const v2f* Sv = (const v2f*)(sS + (u & 1) * SSTR) + lane;
            const v2f* Dv = (const v2f*)(sD + (u & 1) * SSTR) + lane;
            const v2f p0 = Sv[0], p1 = Sv[1], p2 = Sv[2], p3 = Sv[3];
            const v2f q0 = Dv[0], q1 = Dv[1], q2 = Dv[2], q3 = Dv[3];

            // even/odd half-sum trees (pk), r13-proven
            const v2f ts  = (p0 + p1) + (p2 + p3);
            const v2f td  = (q0 + q1) + (q2 + q3);
            const v2f tqs = (p0*p0 + p1*p1) + (p2*p2 + p3*p3);
            const v2f tqd = (q0*q0 + q1*q1) + (q2*q2 + q3*q3);

            const float EOs  = ts.x + ts.y,   EOd  = td.x + td.y;
            const float EOss = tqs.x + tqs.y, EOdd = tqd.x + tqd.y;
            v2f hS, hD, hSS, hDD;
            hS.x  = EOs  - p3.y;          hS.y  = EOs  - p0.x;
            hD.x  = EOd  - q3.y;          hD.y  = EOd  - q0.x;
            hSS.x = EOss - p3.y * p3.y;   hSS.y = EOss - p0.x * p0.x;
            hDD.x = EOdd - q3.y * q3.y;   hDD.y = EOdd - q0.x * q0.x;

            const int sl = u % WIN;       // compile-time (fully unrolled)
            VS  += hS  - rS[sl];   VD  += hD  - rD[sl];
            VSS += hSS - rSS[sl];  VDD += hDD - rDD[sl];
            rS[sl] = hS; rD[sl] = hD; rSS[sl] = hSS; rDD[sl] = hDD;

            if (u >= WIN - 1 && active) {
                const v2f a  = VS * VS, b = VD * VD;
                const v2f pd = a - b,  ps = a + b;
                const v2f A1 = 0.5f * pd + C1v;
                const v2f B1 = 0.5f * ps + C1v;
                const v2f t1 = VSS - VDD,  t2 = VSS + VDD;
                const v2f w1 = 49.0f * t1 - pd;
                const v2f w2 = 49.0f * t2 - ps;
                const v2f A2 = covh * w1 + C2v;
                const v2f B2 = covh * w2 + C2v;
                const v2f N  = A1 * A2, D = B1 * B2;
                const float Dp  = D.x * D.y;
                const float num = fmaf(N.y, D.x, N.x * D.y);
                esum = fmaf(num, __builtin_amdgcn_rcpf(Dp), esum);
            }
        }

        // stage row u+1 AFTER this iter's reads (one fence/iter covers RAW+WAR)
        if (u + 1 < NROWS) WRITER((u + 1) & 3, (u + 1) & 1);

        if (u % WIN == WIN - 1 || u == NROWS - 1) {   // compile-time
            acc += (double)esum;
            esum = 0.f;
        }
    }
#undef LOADR
#undef WRITER
    return acc;
}

// 4 independent waves per block (wave-private LDS regions, no block barriers
// until the final 4-double reduce).
__global__ __launch_bounds__(256, 2) void ssim_stream(
    const float* __restrict__ X, const float* __restrict__ Y,
    const float* __restrict__ dr, double* __restrict__ partial)
{
    __shared__ float  SDbuf[WPB][2][2][TCOLS];   // [wave][slot][s/d][col] = 8704 B
    __shared__ double sred[WPB];

    const int tid  = threadIdx.x;
    const int lane = tid & 63;
    const int wv   = tid >> 6;

    const int task = blockIdx.x * WPB + wv;   // 0..10239
    const int tile = task % NCT;
    const int band = (task / NCT) % NBANDS;
    const int b    = task / (NCT * NBANDS);

    const int r0 = band * BROWS;
    const int tb = tile * 128;

    const int  ocol   = tb + 2 * lane;                  // 2 output cols per lane
    const int  c0     = ocol;                           // own float2 (in-bounds)
    const int  hc     = min(tb + 128 + 2 * (lane & 3), IMW - 2);  // halo cols
    const bool active = (ocol <= OWW - 2);

    const float* Xb = X + (size_t)b * IMH * IMW + (size_t)r0 * IMW;
    const float* Yb = Y + (size_t)b * IMH * IMW + (size_t)r0 * IMW;

    const float drv = dr[b];
    const float C1s = 2401.0f * (0.01f * drv) * (0.01f * drv);
    const float C2s = 2401.0f * (0.03f * drv) * (0.03f * drv);

    float* sS = &SDbuf[wv][0][0][0];
    float* sD = &SDbuf[wv][0][1][0];

    double acc;
    if (band < NBANDS - 1) {
        acc = band_loop<BROWS + WIN - 1>(Xb, Yb, sS, sD, lane, c0, hc,
                                         C1s, C2s, active);          // 26 rows
    } else {
        acc = band_loop<IMH - (NBANDS - 1) * BROWS>(Xb, Yb, sS, sD, lane, c0, hc,
                                                    C1s, C2s, active); // 20 rows
    }

    for (int off = 32; off > 0; off >>= 1)
        acc += __shfl_down(acc, off, 64);
    if (lane == 0) sred[wv] = acc;
    __syncthreads();
    if (tid == 0) {
        double t = 0.0;
        #pragma unroll
        for (int k = 0; k < WPB; ++k) t += sred[k];
        partial[blockIdx.x] = t;
    }
}

__global__ __launch_bounds__(512) void ssim_reduce(
    const double* __restrict__ partial, int n2, float* __restrict__ out)
{
    const double2* p2 = (const double2*)partial;
    double acc = 0.0;
    for (int i = threadIdx.x; i < n2; i += 512) {
        double2 v = p2[i];
        acc += v.x + v.y;
    }
    for (int off = 32; off > 0; off >>= 1)
        acc += __shfl_down(acc, off, 64);
    __shared__ double sred[8];
    if ((threadIdx.x & 63) == 0) sred[threadIdx.x >> 6] = acc;
    __syncthreads();
    if (threadIdx.x == 0) {
        double t = 0.0;
        #pragma unroll
        for (int k = 0; k < 8; ++k) t += sred[k];
        double denom = (double)NB * (double)OHH * (double)OWW;
        out[0] = (float)(t / denom);
    }
}

extern "C" void kernel_launch(void* const* d_in, const int* in_sizes, int n_in,
                              void* d_out, int out_size, void* d_ws, size_t ws_size,
                              hipStream_t stream) {
    const float* X  = (const float*)d_in[0];
    const float* Y  = (const float*)d_in[1];
    const float* dr = (const float*)d_in[2];
    // d_in[3] is w = ones/49; constant-folded in-kernel.
    double* partial = (double*)d_ws;   // 2560 * 8 B = 20 KB scratch

    ssim_stream<<<NBLK, 256, 0, stream>>>(X, Y, dr, partial);
    ssim_reduce<<<1, 512, 0, stream>>>(partial, NBLK / 2, (float*)d_out);
}